// Round 5
// baseline (73.013 us; speedup 1.0000x reference)
//
#include <hip/hip_runtime.h>
#include <hip/hip_cooperative_groups.h>

namespace cg = cooperative_groups;

#define NP 8
#define NB 160
#define NA 32
#define NATYPE 16
#define NPOLY 11
#define MIN_SEP 4
#define NPT 256
#define PSTRIDE 12              // padded poly row (11 + 1), 48B, 16B-aligned
#define NBT 2                   // b1 blocks per workgroup
#define NWG_PER_POSE (NB/NBT)   // 80
#define NWG (NP*NWG_PER_POSE)   // 640
#define ACC_SLOTS (NB*8)        // 1280
#define AVALID (1<<8)
#define DVALID (1<<16)

__device__ __forceinline__ float seg_loop(
    int t, int cnt, const unsigned short* __restrict__ items,
    const float4* __restrict__ accd,
    const float* __restrict__ polyl, const float* __restrict__ paraml,
    const float4 dv[4], float cut, float emin)
{
    float energy = 0.0f;
    for (int i = t; i < cnt; i += 256) {
        const int e = items[i];
        const float4 av = accd[e];
        const int abits = __float_as_int(av.w);
        const int atype = abits & 0xf;
        const int hyb   = (abits >> 4) & 3;
        #pragma unroll
        for (int dn = 0; dn < 4; ++dn) {
            const int dbits = __float_as_int(dv[dn].w);
            if (dbits & DVALID) {   // wave-uniform (prefix validity per b1)
                const float dx = dv[dn].x - av.x;
                const float dy = dv[dn].y - av.y;
                const float dz = dv[dn].z - av.z;
                const float d  = sqrtf(dx * dx + dy * dy + dz * dz + 1e-12f);
                const int pt = (dbits & 0xff) + atype;
                const float4 c0 = *(const float4*)&polyl[pt * PSTRIDE + 0];
                const float4 c1 = *(const float4*)&polyl[pt * PSTRIDE + 4];
                const float4 c2 = *(const float4*)&polyl[pt * PSTRIDE + 8];
                float ev = c0.x;
                ev = ev * d + c0.y; ev = ev * d + c0.z; ev = ev * d + c0.w;
                ev = ev * d + c1.x; ev = ev * d + c1.y; ev = ev * d + c1.z; ev = ev * d + c1.w;
                ev = ev * d + c2.x; ev = ev * d + c2.y; ev = ev * d + c2.z;
                const float w = paraml[pt * 3 + hyb];
                ev = fmaxf(fminf(ev, 0.0f), emin);
                if (d < cut) energy += w * ev;
            }
        }
    }
    return energy;
}

__global__ __launch_bounds__(256, 3) void hbond_kernel(
    const float* __restrict__ coords,
    const int*   __restrict__ coord_off,
    const int*   __restrict__ block_type,
    const int*   __restrict__ min_sep,
    const int*   __restrict__ n_donH,
    const int*   __restrict__ n_acc,
    const int*   __restrict__ donH_inds,
    const int*   __restrict__ acc_inds,
    const int*   __restrict__ donor_type,
    const int*   __restrict__ acceptor_type,
    const int*   __restrict__ acceptor_hyb,
    const float* __restrict__ pair_params,
    const float* __restrict__ pair_poly,
    const float* __restrict__ gp,
    float*       __restrict__ partials,   // ws: NWG floats
    float*       __restrict__ out)        // (P,)
{
    const int t  = threadIdx.x;
    const int p  = blockIdx.x / NWG_PER_POSE;
    const int pr = blockIdx.x % NWG_PER_POSE;
    const int b1a = pr * NBT, b1b = b1a + 1;

    __shared__ __align__(16) float4 accd[ACC_SLOTS];      // 20480
    __shared__ __align__(16) float  polyl[NPT * PSTRIDE]; // 12288
    __shared__ float  paraml[NPT * 3];                    //  3072
    __shared__ unsigned short itemsA[ACC_SLOTS];          //  2560
    __shared__ unsigned short itemsB[ACC_SLOTS];          //  2560
    __shared__ unsigned char okA[NB], okB[NB];            //   320
    __shared__ int  wcA[5][4], wcB[5][4];                 //   160
    __shared__ float wsum[4];

    // ---- tables ----
    for (int i = t; i < NPT * PSTRIDE; i += 256) {
        const int r = i / PSTRIDE, c = i - r * PSTRIDE;
        polyl[i] = (c < NPOLY) ? pair_poly[r * NPOLY + c] : 0.0f;
    }
    for (int i = t; i < NPT * 3; i += 256) paraml[i] = pair_params[i];

    // ---- acceptor staging (gather) ----
    for (int e = t; e < ACC_SLOTS; e += 256) {
        const int b2 = e >> 3, a = e & 7;
        const int bt2 = block_type[p * NB + b2];
        float4 v; int bits = 0;
        if (a < n_acc[bt2]) {
            const int off2  = coord_off[p * NB + b2];
            const int aidx  = acc_inds[bt2 * 8 + a];
            const int atype = acceptor_type[bt2 * 8 + a];
            const int hyb   = acceptor_hyb[bt2 * 8 + a];
            const float* Ac = coords + (size_t)(p * (NB * NA) + off2 + aidx) * 3;
            v.x = Ac[0]; v.y = Ac[1]; v.z = Ac[2];
            bits = (atype & 0xf) | ((hyb & 3) << 4) | AVALID;
        } else { v.x = 1e9f; v.y = 0.0f; v.z = 0.0f; }
        v.w = __int_as_float(bits);
        accd[e] = v;
    }

    // ---- donors -> registers (uniform addresses, broadcast loads) ----
    float4 dA[4], dB[4];
    {
        const int bt1a = block_type[p * NB + b1a], bt1b = block_type[p * NB + b1b];
        const int off1a = coord_off[p * NB + b1a], off1b = coord_off[p * NB + b1b];
        const int nda = n_donH[bt1a], ndb = n_donH[bt1b];
        #pragma unroll
        for (int dn = 0; dn < 4; ++dn) {
            const float* Ha = coords + (size_t)(p * (NB * NA) + off1a + donH_inds[bt1a * 4 + dn]) * 3;
            const float* Hb = coords + (size_t)(p * (NB * NA) + off1b + donH_inds[bt1b * 4 + dn]) * 3;
            dA[dn] = make_float4(Ha[0], Ha[1], Ha[2], __int_as_float(((donor_type[bt1a * 4 + dn] * NATYPE) & 0xff) | ((dn < nda) ? DVALID : 0)));
            dB[dn] = make_float4(Hb[0], Hb[1], Hb[2], __int_as_float(((donor_type[bt1b * 4 + dn] * NATYPE) & 0xff) | ((dn < ndb) ? DVALID : 0)));
        }
    }

    // ---- pair_ok flags ----
    if (t < NB) {
        okA[t] = (t != b1a) && (min_sep[(p * NB + b1a) * NB + t] >= MIN_SEP);
        okB[t] = (t != b1b) && (min_sep[(p * NB + b1b) * NB + t] >= MIN_SEP);
    }

    __syncthreads();

    // ---- build compacted item lists (valid (b2,acc) slots) ----
    unsigned long long mA[5], mB[5];
    #pragma unroll
    for (int r = 0; r < 5; ++r) {
        const int e  = r * 256 + t;
        const int b2 = e >> 3;
        const int av = __float_as_int(accd[e].w) & AVALID;
        mA[r] = __ballot(okA[b2] && av);
        mB[r] = __ballot(okB[b2] && av);
    }
    const int wv = t >> 6, ln = t & 63;
    if (ln == 0) {
        #pragma unroll
        for (int r = 0; r < 5; ++r) { wcA[r][wv] = __popcll(mA[r]); wcB[r][wv] = __popcll(mB[r]); }
    }
    __syncthreads();

    int cntA = 0, cntB = 0;
    {
        const unsigned long long below = (1ull << ln) - 1ull;
        int baseA = 0, baseB = 0;
        #pragma unroll
        for (int r = 0; r < 5; ++r) {
            int preA = baseA, preB = baseB;
            #pragma unroll
            for (int w = 0; w < 4; ++w) {
                if (w < wv) { preA += wcA[r][w]; preB += wcB[r][w]; }
                baseA += wcA[r][w]; baseB += wcB[r][w];
            }
            if ((mA[r] >> ln) & 1) itemsA[preA + __popcll(mA[r] & below)] = (unsigned short)(r * 256 + t);
            if ((mB[r] >> ln) & 1) itemsB[preB + __popcll(mB[r] & below)] = (unsigned short)(r * 256 + t);
        }
        cntA = baseA; cntB = baseB;
    }
    __syncthreads();

    // ---- main loops ----
    const float cut = gp[0], emin = gp[1];
    float energy = 0.0f;
    energy += seg_loop(t, cntA, itemsA, accd, polyl, paraml, dA, cut, emin);
    energy += seg_loop(t, cntB, itemsB, accd, polyl, paraml, dB, cut, emin);

    // ---- reduce 256 -> 1 partial, pure write (no init needed) ----
    #pragma unroll
    for (int off = 32; off >= 1; off >>= 1)
        energy += __shfl_down(energy, off, 64);
    if (ln == 0) wsum[wv] = energy;
    __syncthreads();
    if (t == 0) partials[blockIdx.x] = wsum[0] + wsum[1] + wsum[2] + wsum[3];

    // ---- grid-wide sync, then wg 0 reduces deterministically ----
    cg::this_grid().sync();

    if (blockIdx.x == 0) {
        // 4 waves; wave wv handles poses 2*wv and 2*wv+1 (80 partials each).
        #pragma unroll
        for (int q = 0; q < 2; ++q) {
            const int pose = wv * 2 + q;
            const int base = pose * NWG_PER_POSE;
            float v = partials[base + ln];
            if (ln < NWG_PER_POSE - 64) v += partials[base + 64 + ln];
            #pragma unroll
            for (int off = 32; off >= 1; off >>= 1)
                v += __shfl_down(v, off, 64);
            if (ln == 0) out[pose] = v;
        }
    }
}

extern "C" void kernel_launch(void* const* d_in, const int* in_sizes, int n_in,
                              void* d_out, int out_size, void* d_ws, size_t ws_size,
                              hipStream_t stream) {
    const float* coords        = (const float*)d_in[0];
    // d_in[1] (dispatch) is the full (p, b1, b2) meshgrid — derived from blockIdx.
    const int*   coord_off     = (const int*)  d_in[2];
    const int*   block_type    = (const int*)  d_in[3];
    const int*   min_sep       = (const int*)  d_in[4];
    const int*   n_donH        = (const int*)  d_in[5];
    const int*   n_acc         = (const int*)  d_in[6];
    const int*   donH_inds     = (const int*)  d_in[7];
    const int*   acc_inds      = (const int*)  d_in[8];
    const int*   donor_type    = (const int*)  d_in[9];
    const int*   acceptor_type = (const int*)  d_in[10];
    const int*   acceptor_hyb  = (const int*)  d_in[11];
    const float* pair_params   = (const float*)d_in[12];
    const float* pair_poly     = (const float*)d_in[13];
    const float* gp            = (const float*)d_in[14];
    float*       partials      = (float*)d_ws;   // NWG floats
    float*       out           = (float*)d_out;

    void* args[] = {
        (void*)&coords, (void*)&coord_off, (void*)&block_type, (void*)&min_sep,
        (void*)&n_donH, (void*)&n_acc, (void*)&donH_inds, (void*)&acc_inds,
        (void*)&donor_type, (void*)&acceptor_type, (void*)&acceptor_hyb,
        (void*)&pair_params, (void*)&pair_poly, (void*)&gp,
        (void*)&partials, (void*)&out
    };
    hipLaunchCooperativeKernel((const void*)hbond_kernel,
                               dim3(NWG), dim3(256), args, 0, stream);
}

// Round 6
// 22.286 us; speedup vs baseline: 3.2762x; 3.2762x over previous
//
#include <hip/hip_runtime.h>

#define NP 8
#define NB 160
#define NA 32
#define NATYPE 16
#define NPOLY 11
#define MIN_SEP 4
#define NPT 256
#define PSTRIDE 12              // padded poly row (11 + 1), 48B
#define NBT 2                   // b1 blocks per workgroup
#define NWG_PER_POSE (NB/NBT)   // 80
#define NWG (NP*NWG_PER_POSE)   // 640
#define ACC_SLOTS (NB*8)        // 1280
#define DON_SLOTS (NB*4)        // 640
#define AVALID 0x80             // uchar bit 7; atype bits 0-3, hyb bits 4-5
#define DVALID (1<<16)

// ---- ws layout (bytes) ----
#define WS_ACC_OFF   0                                   // NP*1280 float4 = 163840
#define WS_DON_OFF   (WS_ACC_OFF + NP*ACC_SLOTS*16)      // NP*640 float4  =  81920
#define WS_POLY_OFF  (WS_DON_OFF + NP*DON_SLOTS*16)      // 256*12 float   =  12288
#define WS_PARAM_OFF (WS_POLY_OFF + NPT*PSTRIDE*4)       // 256*3 float    =   3072
#define WS_BITS_OFF  (WS_PARAM_OFF + NPT*3*4)            // NP*1280 uchar  =  10240
#define WS_NEEDED    ((size_t)(WS_BITS_OFF + NP*ACC_SLOTS))

__global__ void zero_out_kernel(float* out) {
    if (threadIdx.x < NP) out[threadIdx.x] = 0.0f;
}

// Build pose-wide acceptor/donor tables + padded poly/params + zero out.
__global__ __launch_bounds__(256) void pre_kernel(
    const float* __restrict__ coords, const int* __restrict__ coord_off,
    const int* __restrict__ block_type, const int* __restrict__ n_donH,
    const int* __restrict__ n_acc, const int* __restrict__ donH_inds,
    const int* __restrict__ acc_inds, const int* __restrict__ donor_type,
    const int* __restrict__ acceptor_type, const int* __restrict__ acceptor_hyb,
    const float* __restrict__ pair_params, const float* __restrict__ pair_poly,
    char* __restrict__ wsb, float* __restrict__ out)
{
    const int gid = blockIdx.x * 256 + threadIdx.x;
    float4* accw  = (float4*)(wsb + WS_ACC_OFF);
    float4* donw  = (float4*)(wsb + WS_DON_OFF);
    float*  polyw = (float*)(wsb + WS_POLY_OFF);
    float*  parw  = (float*)(wsb + WS_PARAM_OFF);
    unsigned char* bitsw = (unsigned char*)(wsb + WS_BITS_OFF);

    if (gid < NP) out[gid] = 0.0f;

    if (gid < NP * ACC_SLOTS) {
        const int p = gid / ACC_SLOTS, rem = gid % ACC_SLOTS;
        const int b2 = rem >> 3, a = rem & 7;
        const int bt2 = block_type[p * NB + b2];
        float4 v; int bits = 0;
        if (a < n_acc[bt2]) {
            const int off2  = coord_off[p * NB + b2];
            const int aidx  = acc_inds[bt2 * 8 + a];
            const int atype = acceptor_type[bt2 * 8 + a];
            const int hyb   = acceptor_hyb[bt2 * 8 + a];
            const float* Ac = coords + (size_t)(p * (NB * NA) + off2 + aidx) * 3;
            v.x = Ac[0]; v.y = Ac[1]; v.z = Ac[2];
            bits = (atype & 0xf) | ((hyb & 3) << 4) | AVALID;
        } else { v.x = 1e9f; v.y = 0.0f; v.z = 0.0f; }
        v.w = __int_as_float(bits);
        accw[gid] = v;
        bitsw[gid] = (unsigned char)bits;
    }
    if (gid < NP * DON_SLOTS) {
        const int p = gid / DON_SLOTS, rem = gid % DON_SLOTS;
        const int b1 = rem >> 2, don = rem & 3;
        const int bt1   = block_type[p * NB + b1];
        const int off1  = coord_off[p * NB + b1];
        const int hatom = donH_inds[bt1 * 4 + don];
        const int dbase = donor_type[bt1 * 4 + don] * NATYPE;
        const float* Hc = coords + (size_t)(p * (NB * NA) + off1 + hatom) * 3;
        float4 v;
        v.x = Hc[0]; v.y = Hc[1]; v.z = Hc[2];
        v.w = __int_as_float((dbase & 0xff) | ((don < n_donH[bt1]) ? DVALID : 0));
        donw[gid] = v;
    }
    if (gid < NPT * PSTRIDE) {
        const int r = gid / PSTRIDE, c = gid - r * PSTRIDE;
        polyw[gid] = (c < NPOLY) ? pair_poly[r * NPOLY + c] : 0.0f;
    }
    if (gid < NPT * 3) parw[gid] = pair_params[gid];
}

// -------- fast kernel: no LDS staging, distance pre-filter --------
__global__ __launch_bounds__(256, 4) void hbond_fast(
    const int*   __restrict__ min_sep,
    const float* __restrict__ gp,
    const char*  __restrict__ wsb,
    float*       __restrict__ out)
{
    const int t  = threadIdx.x;
    const int p  = blockIdx.x / NWG_PER_POSE;
    const int pr = blockIdx.x % NWG_PER_POSE;
    const int b1a = pr * NBT, b1b = b1a + 1;

    const float4* accw  = (const float4*)(wsb + WS_ACC_OFF) + p * ACC_SLOTS;
    const float4* donw  = (const float4*)(wsb + WS_DON_OFF) + p * DON_SLOTS;
    const float4* polyw = (const float4*)(wsb + WS_POLY_OFF);   // 3 float4 per pt
    const float*  parw  = (const float*)(wsb + WS_PARAM_OFF);
    const unsigned char* bitsw = (const unsigned char*)(wsb + WS_BITS_OFF) + p * ACC_SLOTS;

    __shared__ unsigned short itemsA[ACC_SLOTS];   // 2560 B
    __shared__ unsigned short itemsB[ACC_SLOTS];   // 2560 B
    __shared__ unsigned char  okA[NB], okB[NB];    //  320 B
    __shared__ int   wcA[5][4], wcB[5][4];         //  160 B
    __shared__ float wsum[4];

    // donors (uniform broadcast loads)
    float4 dA[4], dB[4];
    #pragma unroll
    for (int dn = 0; dn < 4; ++dn) {
        dA[dn] = donw[b1a * 4 + dn];
        dB[dn] = donw[b1b * 4 + dn];
    }
    const float cut = gp[0], emin = gp[1];

    if (t < NB) {
        okA[t] = (t != b1a) && (min_sep[(p * NB + b1a) * NB + t] >= MIN_SEP);
        okB[t] = (t != b1b) && (min_sep[(p * NB + b1b) * NB + t] >= MIN_SEP);
    }
    __syncthreads();

    // ballot compaction of valid (b2, acc) slots
    unsigned long long mA[5], mB[5];
    #pragma unroll
    for (int r = 0; r < 5; ++r) {
        const int e = r * 256 + t;
        const bool v = (bitsw[e] & AVALID) != 0;
        mA[r] = __ballot(okA[e >> 3] && v);
        mB[r] = __ballot(okB[e >> 3] && v);
    }
    const int wv = t >> 6, ln = t & 63;
    if (ln == 0) {
        #pragma unroll
        for (int r = 0; r < 5; ++r) { wcA[r][wv] = __popcll(mA[r]); wcB[r][wv] = __popcll(mB[r]); }
    }
    __syncthreads();

    int cntA = 0, cntB = 0;
    {
        const unsigned long long below = (1ull << ln) - 1ull;
        int baseA = 0, baseB = 0;
        #pragma unroll
        for (int r = 0; r < 5; ++r) {
            int preA = baseA, preB = baseB;
            #pragma unroll
            for (int w = 0; w < 4; ++w) {
                if (w < wv) { preA += wcA[r][w]; preB += wcB[r][w]; }
                baseA += wcA[r][w]; baseB += wcB[r][w];
            }
            if ((mA[r] >> ln) & 1) itemsA[preA + __popcll(mA[r] & below)] = (unsigned short)(r * 256 + t);
            if ((mB[r] >> ln) & 1) itemsB[preB + __popcll(mB[r] & below)] = (unsigned short)(r * 256 + t);
        }
        cntA = baseA; cntB = baseB;
    }
    __syncthreads();

    float energy = 0.0f;
    #pragma unroll 1
    for (int seg = 0; seg < 2; ++seg) {
        const int cnt = seg ? cntB : cntA;
        const unsigned short* items = seg ? itemsB : itemsA;
        const float4* dv = seg ? dB : dA;
        for (int i = t; i < cnt; i += 256) {
            const int e = items[i];
            const float4 av = accw[e];
            const int abits = __float_as_int(av.w);
            const int atype = abits & 0xf;
            const int hyb   = (abits >> 4) & 3;

            // distance pre-filter: collect rare hits via select chain
            float hd0 = 0, hd1 = 0, hd2 = 0, hd3 = 0;
            int   hp0 = 0, hp1 = 0, hp2 = 0, hp3 = 0;
            int   nh = 0;
            #pragma unroll
            for (int dn = 0; dn < 4; ++dn) {
                const int dbits = __float_as_int(dv[dn].w);
                if (!(dbits & DVALID)) continue;   // wave-uniform
                const float dx = dv[dn].x - av.x;
                const float dy = dv[dn].y - av.y;
                const float dz = dv[dn].z - av.z;
                const float dd = sqrtf(dx * dx + dy * dy + dz * dz + 1e-12f);
                if (dd < cut) {
                    const int pp = (dbits & 0xff) + atype;
                    hd3 = (nh == 3) ? dd : hd3;  hp3 = (nh == 3) ? pp : hp3;
                    hd2 = (nh == 2) ? dd : hd2;  hp2 = (nh == 2) ? pp : hp2;
                    hd1 = (nh == 1) ? dd : hd1;  hp1 = (nh == 1) ? pp : hp1;
                    hd0 = (nh == 0) ? dd : hd0;  hp0 = (nh == 0) ? pp : hp0;
                    ++nh;
                }
            }
            #pragma unroll
            for (int h = 0; h < 4; ++h) {
                if (!__any(h < nh)) break;
                if (h < nh) {
                    const float dd = (h == 0) ? hd0 : (h == 1) ? hd1 : (h == 2) ? hd2 : hd3;
                    const int   pp = (h == 0) ? hp0 : (h == 1) ? hp1 : (h == 2) ? hp2 : hp3;
                    const float4 c0 = polyw[pp * 3 + 0];
                    const float4 c1 = polyw[pp * 3 + 1];
                    const float4 c2 = polyw[pp * 3 + 2];
                    float ev = c0.x;
                    ev = ev * dd + c0.y; ev = ev * dd + c0.z; ev = ev * dd + c0.w;
                    ev = ev * dd + c1.x; ev = ev * dd + c1.y; ev = ev * dd + c1.z; ev = ev * dd + c1.w;
                    ev = ev * dd + c2.x; ev = ev * dd + c2.y; ev = ev * dd + c2.z;
                    const float w = parw[pp * 3 + hyb];
                    ev = fmaxf(fminf(ev, 0.0f), emin);
                    energy += w * ev;
                }
            }
        }
    }

    #pragma unroll
    for (int off = 32; off >= 1; off >>= 1)
        energy += __shfl_down(energy, off, 64);
    if (ln == 0) wsum[wv] = energy;
    __syncthreads();
    if (t == 0) atomicAdd(out + p, wsum[0] + wsum[1] + wsum[2] + wsum[3]);
}

// -------- fallback (proven r3 structure) if ws too small --------
__device__ __forceinline__ float seg_loop_fb(
    int t, int cnt, const unsigned short* __restrict__ items,
    const float4* __restrict__ accd,
    const float* __restrict__ polyl, const float* __restrict__ paraml,
    const float4 dv[4], float cut, float emin)
{
    float energy = 0.0f;
    for (int i = t; i < cnt; i += 256) {
        const int e = items[i];
        const float4 av = accd[e];
        const int abits = __float_as_int(av.w);
        const int atype = abits & 0xf;
        const int hyb   = (abits >> 4) & 3;
        #pragma unroll
        for (int dn = 0; dn < 4; ++dn) {
            const int dbits = __float_as_int(dv[dn].w);
            if (dbits & DVALID) {
                const float dx = dv[dn].x - av.x;
                const float dy = dv[dn].y - av.y;
                const float dz = dv[dn].z - av.z;
                const float d  = sqrtf(dx * dx + dy * dy + dz * dz + 1e-12f);
                const int pt = (dbits & 0xff) + atype;
                const float4 c0 = *(const float4*)&polyl[pt * PSTRIDE + 0];
                const float4 c1 = *(const float4*)&polyl[pt * PSTRIDE + 4];
                const float4 c2 = *(const float4*)&polyl[pt * PSTRIDE + 8];
                float ev = c0.x;
                ev = ev * d + c0.y; ev = ev * d + c0.z; ev = ev * d + c0.w;
                ev = ev * d + c1.x; ev = ev * d + c1.y; ev = ev * d + c1.z; ev = ev * d + c1.w;
                ev = ev * d + c2.x; ev = ev * d + c2.y; ev = ev * d + c2.z;
                const float w = paraml[pt * 3 + hyb];
                ev = fmaxf(fminf(ev, 0.0f), emin);
                if (d < cut) energy += w * ev;
            }
        }
    }
    return energy;
}

__global__ __launch_bounds__(256, 3) void hbond_fallback(
    const float* __restrict__ coords,
    const int*   __restrict__ coord_off,
    const int*   __restrict__ block_type,
    const int*   __restrict__ min_sep,
    const int*   __restrict__ n_donH,
    const int*   __restrict__ n_acc,
    const int*   __restrict__ donH_inds,
    const int*   __restrict__ acc_inds,
    const int*   __restrict__ donor_type,
    const int*   __restrict__ acceptor_type,
    const int*   __restrict__ acceptor_hyb,
    const float* __restrict__ pair_params,
    const float* __restrict__ pair_poly,
    const float* __restrict__ gp,
    float*       __restrict__ out)
{
    const int t  = threadIdx.x;
    const int p  = blockIdx.x / NWG_PER_POSE;
    const int pr = blockIdx.x % NWG_PER_POSE;
    const int b1a = pr * NBT, b1b = b1a + 1;

    __shared__ __align__(16) float4 accd[ACC_SLOTS];
    __shared__ __align__(16) float  polyl[NPT * PSTRIDE];
    __shared__ float  paraml[NPT * 3];
    __shared__ unsigned short itemsA[ACC_SLOTS];
    __shared__ unsigned short itemsB[ACC_SLOTS];
    __shared__ unsigned char okA[NB], okB[NB];
    __shared__ int  wcA[5][4], wcB[5][4];
    __shared__ float wsum[4];

    for (int i = t; i < NPT * PSTRIDE; i += 256) {
        const int r = i / PSTRIDE, c = i - r * PSTRIDE;
        polyl[i] = (c < NPOLY) ? pair_poly[r * NPOLY + c] : 0.0f;
    }
    for (int i = t; i < NPT * 3; i += 256) paraml[i] = pair_params[i];

    for (int e = t; e < ACC_SLOTS; e += 256) {
        const int b2 = e >> 3, a = e & 7;
        const int bt2 = block_type[p * NB + b2];
        float4 v; int bits = 0;
        if (a < n_acc[bt2]) {
            const int off2  = coord_off[p * NB + b2];
            const int aidx  = acc_inds[bt2 * 8 + a];
            const int atype = acceptor_type[bt2 * 8 + a];
            const int hyb   = acceptor_hyb[bt2 * 8 + a];
            const float* Ac = coords + (size_t)(p * (NB * NA) + off2 + aidx) * 3;
            v.x = Ac[0]; v.y = Ac[1]; v.z = Ac[2];
            bits = (atype & 0xf) | ((hyb & 3) << 4) | AVALID;
        } else { v.x = 1e9f; v.y = 0.0f; v.z = 0.0f; }
        v.w = __int_as_float(bits);
        accd[e] = v;
    }

    float4 dA[4], dB[4];
    {
        const int bt1a = block_type[p * NB + b1a], bt1b = block_type[p * NB + b1b];
        const int off1a = coord_off[p * NB + b1a], off1b = coord_off[p * NB + b1b];
        const int nda = n_donH[bt1a], ndb = n_donH[bt1b];
        #pragma unroll
        for (int dn = 0; dn < 4; ++dn) {
            const float* Ha = coords + (size_t)(p * (NB * NA) + off1a + donH_inds[bt1a * 4 + dn]) * 3;
            const float* Hb = coords + (size_t)(p * (NB * NA) + off1b + donH_inds[bt1b * 4 + dn]) * 3;
            dA[dn] = make_float4(Ha[0], Ha[1], Ha[2], __int_as_float(((donor_type[bt1a * 4 + dn] * NATYPE) & 0xff) | ((dn < nda) ? DVALID : 0)));
            dB[dn] = make_float4(Hb[0], Hb[1], Hb[2], __int_as_float(((donor_type[bt1b * 4 + dn] * NATYPE) & 0xff) | ((dn < ndb) ? DVALID : 0)));
        }
    }

    if (t < NB) {
        okA[t] = (t != b1a) && (min_sep[(p * NB + b1a) * NB + t] >= MIN_SEP);
        okB[t] = (t != b1b) && (min_sep[(p * NB + b1b) * NB + t] >= MIN_SEP);
    }
    __syncthreads();

    unsigned long long mA[5], mB[5];
    #pragma unroll
    for (int r = 0; r < 5; ++r) {
        const int e  = r * 256 + t;
        const int av = __float_as_int(accd[e].w) & AVALID;
        mA[r] = __ballot(okA[e >> 3] && av);
        mB[r] = __ballot(okB[e >> 3] && av);
    }
    const int wv = t >> 6, ln = t & 63;
    if (ln == 0) {
        #pragma unroll
        for (int r = 0; r < 5; ++r) { wcA[r][wv] = __popcll(mA[r]); wcB[r][wv] = __popcll(mB[r]); }
    }
    __syncthreads();

    int cntA = 0, cntB = 0;
    {
        const unsigned long long below = (1ull << ln) - 1ull;
        int baseA = 0, baseB = 0;
        #pragma unroll
        for (int r = 0; r < 5; ++r) {
            int preA = baseA, preB = baseB;
            #pragma unroll
            for (int w = 0; w < 4; ++w) {
                if (w < wv) { preA += wcA[r][w]; preB += wcB[r][w]; }
                baseA += wcA[r][w]; baseB += wcB[r][w];
            }
            if ((mA[r] >> ln) & 1) itemsA[preA + __popcll(mA[r] & below)] = (unsigned short)(r * 256 + t);
            if ((mB[r] >> ln) & 1) itemsB[preB + __popcll(mB[r] & below)] = (unsigned short)(r * 256 + t);
        }
        cntA = baseA; cntB = baseB;
    }
    __syncthreads();

    const float cut = gp[0], emin = gp[1];
    float energy = 0.0f;
    energy += seg_loop_fb(t, cntA, itemsA, accd, polyl, paraml, dA, cut, emin);
    energy += seg_loop_fb(t, cntB, itemsB, accd, polyl, paraml, dB, cut, emin);

    #pragma unroll
    for (int off = 32; off >= 1; off >>= 1)
        energy += __shfl_down(energy, off, 64);
    if (ln == 0) wsum[wv] = energy;
    __syncthreads();
    if (t == 0) atomicAdd(out + p, wsum[0] + wsum[1] + wsum[2] + wsum[3]);
}

extern "C" void kernel_launch(void* const* d_in, const int* in_sizes, int n_in,
                              void* d_out, int out_size, void* d_ws, size_t ws_size,
                              hipStream_t stream) {
    const float* coords        = (const float*)d_in[0];
    const int*   coord_off     = (const int*)  d_in[2];
    const int*   block_type    = (const int*)  d_in[3];
    const int*   min_sep       = (const int*)  d_in[4];
    const int*   n_donH        = (const int*)  d_in[5];
    const int*   n_acc         = (const int*)  d_in[6];
    const int*   donH_inds     = (const int*)  d_in[7];
    const int*   acc_inds      = (const int*)  d_in[8];
    const int*   donor_type    = (const int*)  d_in[9];
    const int*   acceptor_type = (const int*)  d_in[10];
    const int*   acceptor_hyb  = (const int*)  d_in[11];
    const float* pair_params   = (const float*)d_in[12];
    const float* pair_poly     = (const float*)d_in[13];
    const float* gp            = (const float*)d_in[14];
    float*       out           = (float*)d_out;
    char*        wsb           = (char*)d_ws;

    if (ws_size >= WS_NEEDED) {
        pre_kernel<<<(NP * ACC_SLOTS + 255) / 256, 256, 0, stream>>>(
            coords, coord_off, block_type, n_donH, n_acc, donH_inds, acc_inds,
            donor_type, acceptor_type, acceptor_hyb, pair_params, pair_poly,
            wsb, out);
        hbond_fast<<<NWG, 256, 0, stream>>>(min_sep, gp, wsb, out);
    } else {
        zero_out_kernel<<<1, 64, 0, stream>>>(out);
        hbond_fallback<<<NWG, 256, 0, stream>>>(
            coords, coord_off, block_type, min_sep,
            n_donH, n_acc, donH_inds, acc_inds,
            donor_type, acceptor_type, acceptor_hyb,
            pair_params, pair_poly, gp, out);
    }
}

// Round 7
// 12.192 us; speedup vs baseline: 5.9888x; 1.8280x over previous
//
#include <hip/hip_runtime.h>

#define NP 8
#define NB 160
#define NA 32
#define NATYPE 16
#define NPOLY 11
#define MIN_SEP 4
#define DVALID (1 << 16)

// main: one wg per (pose, b1). Writes one partial per wg to ws (pure write).
__global__ __launch_bounds__(256) void hbond_main(
    const float* __restrict__ coords,        // (P, N*A, 3)
    const int*   __restrict__ coord_off,     // (P, N)
    const int*   __restrict__ block_type,    // (P, N)
    const int*   __restrict__ min_sep,       // (P, N, N)
    const int*   __restrict__ n_donH,        // (BT,)
    const int*   __restrict__ n_acc,         // (BT,)
    const int*   __restrict__ donH_inds,     // (BT, 4)
    const int*   __restrict__ acc_inds,      // (BT, 8)
    const int*   __restrict__ donor_type,    // (BT, 4)
    const int*   __restrict__ acceptor_type, // (BT, 8)
    const int*   __restrict__ acceptor_hyb,  // (BT, 8)
    const float* __restrict__ pair_params,   // (256, 3)
    const float* __restrict__ pair_poly,     // (256, 11)
    const float* __restrict__ gp,            // (4,)
    float*       __restrict__ partials)      // (NP*NB,)
{
    const int t  = threadIdx.x;
    const int p  = blockIdx.x / NB;
    const int b1 = blockIdx.x - p * NB;

    __shared__ int4  b2info[NB];   // (bt2, off2, n_acc, pad) 2560 B
    __shared__ int   b2list[NB];   //  640 B
    __shared__ int   wc[4];
    __shared__ float wsum[4];

    const float cut  = gp[0];
    const float emin = gp[1];

    // ---- per-b2 metadata + pair_ok (t < 160) ----
    bool ok = false;
    if (t < NB) {
        const int bt2  = block_type[p * NB + t];
        const int off2 = coord_off[p * NB + t];
        const int na   = n_acc[bt2];
        ok = (t != b1) && (min_sep[(p * NB + b1) * NB + t] >= MIN_SEP);
        b2info[t] = make_int4(bt2, off2, na, 0);
    }

    // ---- donors for b1 (wave-uniform scalar loads) ----
    const int bt1  = block_type[p * NB + b1];
    const int off1 = coord_off[p * NB + b1];
    const int nd   = n_donH[bt1];
    float4 dv[4];
    #pragma unroll
    for (int dn = 0; dn < 4; ++dn) {
        const int hatom = donH_inds[bt1 * 4 + dn];
        const int dbase = donor_type[bt1 * 4 + dn] * NATYPE;
        const float* Hc = coords + (size_t)(p * (NB * NA) + off1 + hatom) * 3;
        dv[dn] = make_float4(Hc[0], Hc[1], Hc[2],
                             __int_as_float((dbase & 0xff) | ((dn < nd) ? DVALID : 0)));
    }

    // ---- compact b2 list (single ballot round) ----
    const unsigned long long m = __ballot(ok);
    const int wv = t >> 6, ln = t & 63;
    if (ln == 0) wc[wv] = __popcll(m);
    __syncthreads();

    int pre = 0, cnt = 0;
    #pragma unroll
    for (int w = 0; w < 4; ++w) {
        cnt += wc[w];
        if (w < wv) pre += wc[w];
    }
    if (ok) b2list[pre + __popcll(m & ((1ull << ln) - 1ull))] = t;
    __syncthreads();

    // ---- main loop over cnt*8 acceptor slots ----
    float energy = 0.0f;
    const int cnt8 = cnt * 8;
    for (int i = t; i < cnt8; i += 256) {
        const int b2 = b2list[i >> 3];
        const int a  = i & 7;
        const int4 info = b2info[b2];

        float hd0 = 0, hd1 = 0, hd2 = 0, hd3 = 0;
        int   hp0 = 0, hp1 = 0, hp2 = 0, hp3 = 0;
        int   nh = 0, hyb = 0;

        if (a < info.z) {
            const int ai    = acc_inds[info.x * 8 + a];
            const int atype = acceptor_type[info.x * 8 + a];
            hyb             = acceptor_hyb[info.x * 8 + a];
            const float* Ac = coords + (size_t)(p * (NB * NA) + info.y + ai) * 3;
            const float ax = Ac[0], ay = Ac[1], az = Ac[2];

            #pragma unroll
            for (int dn = 0; dn < 4; ++dn) {
                const int dbits = __float_as_int(dv[dn].w);
                if (!(dbits & DVALID)) continue;   // wave-uniform
                const float dx = dv[dn].x - ax;
                const float dy = dv[dn].y - ay;
                const float dz = dv[dn].z - az;
                const float dd = sqrtf(dx * dx + dy * dy + dz * dz + 1e-12f);
                if (dd < cut) {
                    const int pp = (dbits & 0xff) + atype;
                    hd3 = (nh == 3) ? dd : hd3;  hp3 = (nh == 3) ? pp : hp3;
                    hd2 = (nh == 2) ? dd : hd2;  hp2 = (nh == 2) ? pp : hp2;
                    hd1 = (nh == 1) ? dd : hd1;  hp1 = (nh == 1) ? pp : hp1;
                    hd0 = (nh == 0) ? dd : hd0;  hp0 = (nh == 0) ? pp : hp0;
                    ++nh;
                }
            }
        }

        // rare Horner path (~1% of slots)
        #pragma unroll
        for (int h = 0; h < 4; ++h) {
            if (!__any(h < nh)) break;
            if (h < nh) {
                const float dd = (h == 0) ? hd0 : (h == 1) ? hd1 : (h == 2) ? hd2 : hd3;
                const int   pp = (h == 0) ? hp0 : (h == 1) ? hp1 : (h == 2) ? hp2 : hp3;
                const float* c = pair_poly + pp * NPOLY;
                float ev = c[0];
                #pragma unroll
                for (int k = 1; k < NPOLY; ++k) ev = ev * dd + c[k];
                const float w = pair_params[pp * 3 + hyb];
                ev = fmaxf(fminf(ev, 0.0f), emin);
                energy += w * ev;
            }
        }
    }

    // ---- reduce 256 -> 1 partial (pure write, no init needed) ----
    #pragma unroll
    for (int off = 32; off >= 1; off >>= 1)
        energy += __shfl_down(energy, off, 64);
    if (ln == 0) wsum[wv] = energy;
    __syncthreads();
    if (t == 0) partials[blockIdx.x] = wsum[0] + wsum[1] + wsum[2] + wsum[3];
}

// reduce: 1 wg; wave wv sums poses 2wv, 2wv+1 (160 partials each). Pure writes.
__global__ __launch_bounds__(256) void hbond_reduce(
    const float* __restrict__ partials, float* __restrict__ out)
{
    const int wv = threadIdx.x >> 6, ln = threadIdx.x & 63;
    #pragma unroll
    for (int q = 0; q < 2; ++q) {
        const int pose = wv * 2 + q;
        const float* base = partials + pose * NB;
        float v = base[ln] + base[64 + ln] + ((ln < 32) ? base[128 + ln] : 0.0f);
        #pragma unroll
        for (int off = 32; off >= 1; off >>= 1)
            v += __shfl_down(v, off, 64);
        if (ln == 0) out[pose] = v;
    }
}

extern "C" void kernel_launch(void* const* d_in, const int* in_sizes, int n_in,
                              void* d_out, int out_size, void* d_ws, size_t ws_size,
                              hipStream_t stream) {
    const float* coords        = (const float*)d_in[0];
    // d_in[1] (dispatch) is the full (p, b1, b2) meshgrid — derived from blockIdx.
    const int*   coord_off     = (const int*)  d_in[2];
    const int*   block_type    = (const int*)  d_in[3];
    const int*   min_sep       = (const int*)  d_in[4];
    const int*   n_donH        = (const int*)  d_in[5];
    const int*   n_acc         = (const int*)  d_in[6];
    const int*   donH_inds     = (const int*)  d_in[7];
    const int*   acc_inds      = (const int*)  d_in[8];
    const int*   donor_type    = (const int*)  d_in[9];
    const int*   acceptor_type = (const int*)  d_in[10];
    const int*   acceptor_hyb  = (const int*)  d_in[11];
    const float* pair_params   = (const float*)d_in[12];
    const float* pair_poly     = (const float*)d_in[13];
    const float* gp            = (const float*)d_in[14];
    float*       partials      = (float*)d_ws;   // NP*NB floats = 5120 B
    float*       out           = (float*)d_out;

    hbond_main<<<NP * NB, 256, 0, stream>>>(
        coords, coord_off, block_type, min_sep,
        n_donH, n_acc, donH_inds, acc_inds,
        donor_type, acceptor_type, acceptor_hyb,
        pair_params, pair_poly, gp, partials);

    hbond_reduce<<<1, 256, 0, stream>>>(partials, out);
}